// Round 5
// baseline (56.836 us; speedup 1.0000x reference)
//
#include <hip/hip_runtime.h>
#include <math.h>

#define D_DIM 128
#define M_CLUSTERS 64
#define ROWS 64           // rows per block = 4 waves x 16 rows
#define BLOCK 256
#define RBLOCK 256

typedef __bf16 bf16x8 __attribute__((ext_vector_type(8)));
typedef float f32x4 __attribute__((ext_vector_type(4)));

union B8 {
    int4 i;
    bf16x8 b;
};

__device__ __forceinline__ float zval(float sq) {
    float dd = sqrtf(fmaxf(sq, 0.0f));
    float sg = __fdividef(1.0f, 1.0f + __expf(dd));
    return -__logf(sg + 1e-8f);
}

// Prep: muB4 = bf16(mus) linear [64 clusters][16 slots of 16B]; m2 = ||mu||^2 f32.
__global__ void iso_prep(const float4* __restrict__ mus4, int4* __restrict__ muB4,
                         float* __restrict__ m2) {
    const int t = threadIdx.x;
#pragma unroll
    for (int i = 0; i < 4; ++i) {
        int f = i * 256 + t;               // 1024 chunks of 8 f32
        float4 v0 = mus4[f * 2 + 0];
        float4 v1 = mus4[f * 2 + 1];
        B8 p;
        p.b[0] = (__bf16)v0.x; p.b[1] = (__bf16)v0.y;
        p.b[2] = (__bf16)v0.z; p.b[3] = (__bf16)v0.w;
        p.b[4] = (__bf16)v1.x; p.b[5] = (__bf16)v1.y;
        p.b[6] = (__bf16)v1.z; p.b[7] = (__bf16)v1.w;
        muB4[f] = p.i;
    }
    if (t < M_CLUSTERS) {
        const float4* mv = mus4 + t * (D_DIM / 4);
        float s = 0.f;
#pragma unroll
        for (int d = 0; d < D_DIM / 4; ++d) {
            float4 v = mv[d];
            s = fmaf(v.x, v.x, s);
            s = fmaf(v.y, v.y, s);
            s = fmaf(v.z, v.z, s);
            s = fmaf(v.w, v.w, s);
        }
        m2[t] = s;
    }
}

// Main: 16 rows per wave (acc[4] 16x16 tiles over 64 clusters). All global
// loads (X, r, m2) issued up-front for MLP; bf16 convert in-reg; fused epilogue.
__global__ __launch_bounds__(BLOCK, 4) void iso_main(
        const float4* __restrict__ X4, const float* __restrict__ r,
        const int4* __restrict__ muB4, const float* __restrict__ m2g,
        float* __restrict__ partials, int N) {
    __shared__ float pl[BLOCK];

    const int tid = threadIdx.x;
    const int lane = tid & 63;
    const int la = lane & 15;
    const int lg = lane >> 4;
    const int w = tid >> 6;
    const int row0 = blockIdx.x * ROWS + w * 16;   // wave's 16 rows
    const int arow = row0 + la;                    // this lane's A row

    // 1) All X loads up-front: 8 x dwordx4 (lane holds row arow, k-chunks lg*8
    //    within each 32-wide kk block).
    float4 xv[8];
#pragma unroll
    for (int i = 0; i < 8; ++i) xv[i] = make_float4(0.f, 0.f, 0.f, 0.f);
    if (arow < N) {
        const float4* xp = X4 + (size_t)arow * 32 + lg * 2;
#pragma unroll
        for (int kk = 0; kk < 4; ++kk) {
            xv[kk * 2 + 0] = xp[kk * 8 + 0];
            xv[kk * 2 + 1] = xp[kk * 8 + 1];
        }
    }

    // 2) r loads up-front (independent chain; epilogue layout col=la, row=lg*4+q).
    float rv[4][4];
#pragma unroll
    for (int q = 0; q < 4; ++q)
#pragma unroll
        for (int cb = 0; cb < 4; ++cb) rv[q][cb] = 0.f;
    const int erow = row0 + lg * 4;
#pragma unroll
    for (int q = 0; q < 4; ++q) {
        if (erow + q < N) {
            const float* rr = r + (size_t)(erow + q) * M_CLUSTERS + la;
#pragma unroll
            for (int cb = 0; cb < 4; ++cb) rv[q][cb] = rr[cb * 16];
        }
    }

    float m2r[4];
#pragma unroll
    for (int cb = 0; cb < 4; ++cb) m2r[cb] = m2g[cb * 16 + la];

    // 3) K-loop: convert + x2 + 4 B-frag loads (L1-resident) + 4 MFMA per kk.
    f32x4 acc[4];
#pragma unroll
    for (int cb = 0; cb < 4; ++cb)
#pragma unroll
        for (int q = 0; q < 4; ++q) acc[cb][q] = 0.f;
    float x2 = 0.f;

#pragma unroll
    for (int kk = 0; kk < 4; ++kk) {
        float xf[8] = {xv[kk * 2].x,     xv[kk * 2].y,     xv[kk * 2].z,     xv[kk * 2].w,
                       xv[kk * 2 + 1].x, xv[kk * 2 + 1].y, xv[kk * 2 + 1].z, xv[kk * 2 + 1].w};
        B8 a;
#pragma unroll
        for (int j = 0; j < 8; ++j) a.b[j] = (__bf16)xf[j];
#pragma unroll
        for (int j = 0; j < 8; ++j) x2 = fmaf(xf[j], xf[j], x2);
        B8 b[4];
#pragma unroll
        for (int cb = 0; cb < 4; ++cb)
            b[cb].i = muB4[(cb * 16 + la) * 16 + kk * 4 + lg];
#pragma unroll
        for (int cb = 0; cb < 4; ++cb)
            acc[cb] = __builtin_amdgcn_mfma_f32_16x16x32_bf16(a.b, b[cb].b, acc[cb], 0, 0, 0);
    }

    // x2: lane (la,lg) holds quarter of row la -> reduce over lg, broadcast.
    x2 += __shfl_xor(x2, 16, 64);
    x2 += __shfl_xor(x2, 32, 64);
    float x2r[4];
#pragma unroll
    for (int q = 0; q < 4; ++q) x2r[q] = __shfl(x2, lg * 4 + q, 64);

    // Epilogue: OOB rows have rv=0 and sq=m2>=0 -> finite zval * 0 = 0.
    float partial = 0.f;
#pragma unroll
    for (int q = 0; q < 4; ++q)
#pragma unroll
        for (int cb = 0; cb < 4; ++cb) {
            float sq = x2r[q] + m2r[cb] - 2.0f * acc[cb][q];
            partial = fmaf(rv[q][cb], zval(sq), partial);
        }

    // Block reduce.
    pl[tid] = partial;
    __syncthreads();
    if (tid < 64) {
        float s = pl[lane] + pl[64 + lane] + pl[128 + lane] + pl[192 + lane];
#pragma unroll
        for (int off = 32; off > 0; off >>= 1)
            s += __shfl_down(s, off, 64);
        if (lane == 0) partials[blockIdx.x] = s;
    }
}

// Deterministic fixed-order final reduction.
__global__ void iso_reduce(const float* __restrict__ partials, int nblocks,
                           float* __restrict__ out, float invN) {
    float s = 0.f;
    for (int i = threadIdx.x; i < nblocks; i += RBLOCK) s += partials[i];
#pragma unroll
    for (int off = 32; off > 0; off >>= 1)
        s += __shfl_down(s, off, 64);
    __shared__ float wsum[RBLOCK / 64];
    const int lane = threadIdx.x & 63;
    const int wid = threadIdx.x >> 6;
    if (lane == 0) wsum[wid] = s;
    __syncthreads();
    if (threadIdx.x == 0)
        out[0] = (wsum[0] + wsum[1] + wsum[2] + wsum[3]) * invN;
}

extern "C" void kernel_launch(void* const* d_in, const int* in_sizes, int n_in,
                              void* d_out, int out_size, void* d_ws, size_t ws_size,
                              hipStream_t stream) {
    const float* X = (const float*)d_in[0];    // [N,128]
    const float* r = (const float*)d_in[1];    // [N,64]
    const float* mus = (const float*)d_in[2];  // [64,128]
    const int N = in_sizes[0] / D_DIM;

    // ws: muB4 (1024 int4 = 16KB) | m2 (64 f32) | partials (nblocks f32)
    int4* muB4 = (int4*)d_ws;
    float* m2 = (float*)((char*)d_ws + 16384);
    float* partials = m2 + M_CLUSTERS;

    const int nblocks = (N + ROWS - 1) / ROWS;

    hipLaunchKernelGGL(iso_prep, dim3(1), dim3(256), 0, stream,
                       (const float4*)mus, muB4, m2);
    hipLaunchKernelGGL(iso_main, dim3(nblocks), dim3(BLOCK), 0, stream,
                       (const float4*)X, r, muB4, m2, partials, N);
    hipLaunchKernelGGL(iso_reduce, dim3(1), dim3(RBLOCK), 0, stream,
                       partials, nblocks, (float*)d_out, 1.0f / (float)N);
}

// Round 6
// 42.756 us; speedup vs baseline: 1.3293x; 1.3293x over previous
//
#include <hip/hip_runtime.h>
#include <math.h>

#define D_DIM 128
#define M_CLUSTERS 64
#define ROWS 64           // rows per block = 4 waves x 16 rows
#define BLOCK 256
#define RBLOCK 256

typedef __bf16 bf16x8 __attribute__((ext_vector_type(8)));
typedef float f32x4 __attribute__((ext_vector_type(4)));

union B8 {
    int4 i;
    bf16x8 b;
};

__device__ __forceinline__ float zval(float sq) {
    float dd = sqrtf(fmaxf(sq, 0.0f));
    float sg = __fdividef(1.0f, 1.0f + __expf(dd));
    return -__logf(sg + 1e-8f);
}

// Async global->LDS, 16B per lane: lds gets base + lane*16 (HW rule, m97/m104).
__device__ __forceinline__ void gload16(const void* g, void* l) {
    __builtin_amdgcn_global_load_lds(
        (const __attribute__((address_space(1))) unsigned int*)g,
        (__attribute__((address_space(3))) unsigned int*)l, 16, 0, 0);
}

// Prep (grid=4): muB4 = bf16(mus) [64 clusters][16 slots of 16B]; m2 = ||mu||^2 f32.
__global__ void iso_prep(const float4* __restrict__ mus4, int4* __restrict__ muB4,
                         float* __restrict__ m2) {
    const int f = blockIdx.x * 256 + threadIdx.x;   // 1024 chunks of 8 f32
    float4 v0 = mus4[f * 2 + 0];
    float4 v1 = mus4[f * 2 + 1];
    B8 p;
    p.b[0] = (__bf16)v0.x; p.b[1] = (__bf16)v0.y;
    p.b[2] = (__bf16)v0.z; p.b[3] = (__bf16)v0.w;
    p.b[4] = (__bf16)v1.x; p.b[5] = (__bf16)v1.y;
    p.b[6] = (__bf16)v1.z; p.b[7] = (__bf16)v1.w;
    muB4[f] = p.i;
    if (blockIdx.x == 0 && threadIdx.x < M_CLUSTERS) {
        const float4* mv = mus4 + threadIdx.x * (D_DIM / 4);
        float s = 0.f;
#pragma unroll
        for (int d = 0; d < D_DIM / 4; ++d) {
            float4 v = mv[d];
            s = fmaf(v.x, v.x, s);
            s = fmaf(v.y, v.y, s);
            s = fmaf(v.z, v.z, s);
            s = fmaf(v.w, v.w, s);
        }
        m2[threadIdx.x] = s;
    }
}

// Main: per-wave X tile via LDS-DMA (pre-swizzled source, swizzled read),
// mus tile via LDS-DMA, r/m2 in regs issued under the DMA; one drain; MFMA.
__global__ __launch_bounds__(BLOCK, 4) void iso_main(
        const float* __restrict__ X, const float* __restrict__ r,
        const int4* __restrict__ muB4, const float* __restrict__ m2g,
        float* __restrict__ partials, int N) {
    // xs: [64 rows][512B] (wave w owns rows w*16..); bs: [64 clusters][256B].
    __shared__ __align__(16) char lds_raw[ROWS * 512 + M_CLUSTERS * 256];  // 48 KB
    __shared__ float pl[BLOCK];

    const int tid = threadIdx.x;
    const int lane = tid & 63;
    const int la = lane & 15;
    const int lg = lane >> 4;
    const int w = tid >> 6;
    const int rowbase = blockIdx.x * ROWS;

    char* xs = lds_raw;
    char* bs = lds_raw + ROWS * 512;

    // ---- Phase 1: issue all LDS-DMA (queue lives in vmcnt, zero VGPR) ----
    // X: wave w stages its 16 rows as 8 chunks (1KB = 2 rows). Source slot is
    // pre-swizzled with the same involution the reads use (rule #21).
#pragma unroll
    for (int c = 0; c < 8; ++c) {
        int rr = c * 2 + (lane >> 5);
        int grow = rowbase + w * 16 + rr;
        grow = grow < N ? grow : N - 1;
        int slot = (lane & 31) ^ (rr & 7);
        gload16(X + (size_t)grow * D_DIM + slot * 4,
                xs + (size_t)w * 8192 + c * 1024);
    }
    // mus: wave w stages chunks w*4..w*4+3 (1KB = 4 clusters of 256B).
#pragma unroll
    for (int i = 0; i < 4; ++i) {
        int k = w * 4 + i;
        int c = k * 4 + (lane >> 4);
        int slot = (lane & 15) ^ (c & 7);
        gload16(muB4 + c * 16 + slot, bs + k * 1024);
    }

    // ---- Phase 2: register loads overlap the DMA latency ----
    float rv[4][4];
    const int erow = rowbase + w * 16 + lg * 4;
#pragma unroll
    for (int q = 0; q < 4; ++q) {
        int rrow = erow + q;
        const float* rr_ = r + (size_t)(rrow < N ? rrow : N - 1) * M_CLUSTERS + la;
#pragma unroll
        for (int cb = 0; cb < 4; ++cb)
            rv[q][cb] = (rrow < N) ? rr_[cb * 16] : 0.f;
    }
    float m2r[4];
#pragma unroll
    for (int cb = 0; cb < 4; ++cb) m2r[cb] = m2g[cb * 16 + la];

    // ---- Phase 3: single drain (covers DMA + reg loads), block barrier ----
    asm volatile("s_waitcnt vmcnt(0)" ::: "memory");
    __syncthreads();

    // ---- Phase 4: K-loop from LDS ----
    f32x4 acc[4];
#pragma unroll
    for (int cb = 0; cb < 4; ++cb)
#pragma unroll
        for (int q = 0; q < 4; ++q) acc[cb][q] = 0.f;
    float x2 = 0.f;

    const char* xw = xs + (size_t)w * 8192;
#pragma unroll
    for (int kk = 0; kk < 4; ++kk) {
        int s0 = kk * 8 + lg * 2;
        float4 xa = *(const float4*)(xw + la * 512 + ((s0) ^ (la & 7)) * 16);
        float4 xb = *(const float4*)(xw + la * 512 + ((s0 + 1) ^ (la & 7)) * 16);
        B8 a;
        a.b[0] = (__bf16)xa.x; a.b[1] = (__bf16)xa.y;
        a.b[2] = (__bf16)xa.z; a.b[3] = (__bf16)xa.w;
        a.b[4] = (__bf16)xb.x; a.b[5] = (__bf16)xb.y;
        a.b[6] = (__bf16)xb.z; a.b[7] = (__bf16)xb.w;
        x2 = fmaf(xa.x, xa.x, x2); x2 = fmaf(xa.y, xa.y, x2);
        x2 = fmaf(xa.z, xa.z, x2); x2 = fmaf(xa.w, xa.w, x2);
        x2 = fmaf(xb.x, xb.x, x2); x2 = fmaf(xb.y, xb.y, x2);
        x2 = fmaf(xb.z, xb.z, x2); x2 = fmaf(xb.w, xb.w, x2);
        B8 b[4];
#pragma unroll
        for (int cb = 0; cb < 4; ++cb) {
            int cc = cb * 16 + la;
            int t = (kk * 4 + lg) ^ (cc & 7);
            b[cb].i = *(const int4*)(bs + cc * 256 + t * 16);
        }
#pragma unroll
        for (int cb = 0; cb < 4; ++cb)
            acc[cb] = __builtin_amdgcn_mfma_f32_16x16x32_bf16(a.b, b[cb].b,
                                                              acc[cb], 0, 0, 0);
    }

    // x2: lane (la,lg) holds quarter of row la -> reduce over lg, then fetch
    // the x2 of epilogue rows lg*4+q (live at lane index lg*4+q).
    x2 += __shfl_xor(x2, 16, 64);
    x2 += __shfl_xor(x2, 32, 64);
    float x2r[4];
#pragma unroll
    for (int q = 0; q < 4; ++q) x2r[q] = __shfl(x2, lg * 4 + q, 64);

    // Epilogue: C/D layout col=la, row=lg*4+q (m89-verified; absmax=0 r3-r5).
    float partial = 0.f;
#pragma unroll
    for (int q = 0; q < 4; ++q)
#pragma unroll
        for (int cb = 0; cb < 4; ++cb) {
            float sq = x2r[q] + m2r[cb] - 2.0f * acc[cb][q];
            partial = fmaf(rv[q][cb], zval(sq), partial);
        }

    // Block reduce.
    pl[tid] = partial;
    __syncthreads();
    if (tid < 64) {
        float s = pl[lane] + pl[64 + lane] + pl[128 + lane] + pl[192 + lane];
#pragma unroll
        for (int off = 32; off > 0; off >>= 1)
            s += __shfl_down(s, off, 64);
        if (lane == 0) partials[blockIdx.x] = s;
    }
}

// Deterministic fixed-order final reduction.
__global__ void iso_reduce(const float* __restrict__ partials, int nblocks,
                           float* __restrict__ out, float invN) {
    float s = 0.f;
    for (int i = threadIdx.x; i < nblocks; i += RBLOCK) s += partials[i];
#pragma unroll
    for (int off = 32; off > 0; off >>= 1)
        s += __shfl_down(s, off, 64);
    __shared__ float wsum[RBLOCK / 64];
    const int lane = threadIdx.x & 63;
    const int wid = threadIdx.x >> 6;
    if (lane == 0) wsum[wid] = s;
    __syncthreads();
    if (threadIdx.x == 0)
        out[0] = (wsum[0] + wsum[1] + wsum[2] + wsum[3]) * invN;
}

extern "C" void kernel_launch(void* const* d_in, const int* in_sizes, int n_in,
                              void* d_out, int out_size, void* d_ws, size_t ws_size,
                              hipStream_t stream) {
    const float* X = (const float*)d_in[0];    // [N,128]
    const float* r = (const float*)d_in[1];    // [N,64]
    const float* mus = (const float*)d_in[2];  // [64,128]
    const int N = in_sizes[0] / D_DIM;

    // ws: muB4 (1024 int4 = 16KB) | m2 (64 f32) | partials (nblocks f32)
    int4* muB4 = (int4*)d_ws;
    float* m2 = (float*)((char*)d_ws + 16384);
    float* partials = m2 + M_CLUSTERS;

    const int nblocks = (N + ROWS - 1) / ROWS;

    hipLaunchKernelGGL(iso_prep, dim3(4), dim3(256), 0, stream,
                       (const float4*)mus, muB4, m2);
    hipLaunchKernelGGL(iso_main, dim3(nblocks), dim3(BLOCK), 0, stream,
                       X, r, muB4, m2, partials, N);
    hipLaunchKernelGGL(iso_reduce, dim3(1), dim3(RBLOCK), 0, stream,
                       partials, nblocks, (float*)d_out, 1.0f / (float)N);
}